// Round 2
// baseline (682.771 us; speedup 1.0000x reference)
//
#include <hip/hip_runtime.h>

// FilteredNoise: DDSP filtered noise, FFT-free formulation.
// zp_ir[t] = (1/129)(fr0 + 2*sum_{k=1..64} fr_k cos(2*pi*k*t/129)), even-symmetric
// wir[j]   = hann_periodic(j,129) * zp_ir[(j-64) mod 129]   // roll by FCL-1 = 64!
// filtered[t] = sum_k wir[k]*n2[t-k]  (linear conv, len 192)
// out[b, 64*fp + r] = sum_{dd=0..2, fp-dd>=0} conv(frame fp-dd)[64*dd + r]

#define NB 64
#define FTOT 4097
#define FCL 65
#define FL 64
#define IRLEN 129
#define SAMPLES 262144
#define OUT_FRAMES 4096          // frames 0..4095 produce retained output
#define G 8                      // output frames per block
#define NF (G + 2)               // staged frames per block
#define WSTRIDE 132
#define BLOCKS_PER_B (OUT_FRAMES / G)   // 512

__device__ __forceinline__ float mod_sigmoid(float x) {
    float s = 1.0f / (1.0f + __expf(-x));
    // s^ln(10) = exp(ln(10)*ln(s))
    return 2.0f * __expf(2.302585092994046f * __logf(s)) + 1e-7f;
}

__global__ __launch_bounds__(256) void fn_kernel(
    const float* __restrict__ coeff,   // (64, 4097, 65)
    const float* __restrict__ noise,   // (64, 4097, 64)
    float* __restrict__ out)           // (64, 262144)
{
    __shared__ float costab[IRLEN];          // cos(2*pi*m/129)
    __shared__ float frS[NF * FCL];          // modified-sigmoid spectra
    __shared__ float zpS[NF * FCL];          // half zero-phase IR (t=0..64)
    __shared__ float nS[NF * FL];            // noise*2-1
    __shared__ float wirS[NF * WSTRIDE];     // windowed linear-phase IR

    const int tid = threadIdx.x;
    const int blk = blockIdx.x;
    const int b   = blk / BLOCKS_PER_B;
    const int cg  = blk % BLOCKS_PER_B;
    const int fp0 = cg * G;                  // first output frame of this block
    const int fbase = fp0 - 2;               // first staged frame (may be <0)

    // Phase 0: cos table
    if (tid < IRLEN) {
        costab[tid] = __cosf(6.283185307179586f * (float)tid * (1.0f / 129.0f));
    }

    // Phase 1: load coeffs -> fr (650 contiguous floats per block)
    for (int i = tid; i < NF * FCL; i += 256) {
        int q = i / FCL, k = i - q * FCL;
        int f = fbase + q; if (f < 0) f = 0;             // clamp; guarded at conv
        frS[i] = mod_sigmoid(coeff[((size_t)b * FTOT + f) * FCL + k]);
    }
    // Phase 1b: load noise (640 contiguous floats)
    for (int i = tid; i < NF * FL; i += 256) {
        int q = i >> 6, s = i & 63;
        int f = fbase + q; if (f < 0) f = 0;
        nS[i] = 2.0f * noise[((size_t)b * FTOT + f) * FL + s] - 1.0f;
    }
    __syncthreads();

    // Phase 2: half cosine transform: zp[q][d], d in [0,65)
    for (int i = tid; i < NF * FCL; i += 256) {
        int q = i / FCL, d = i - q * FCL;
        const float* fq = &frS[q * FCL];
        float acc = fq[0];
        int m = 0;
        #pragma unroll 8
        for (int k = 1; k < FCL; ++k) {
            m += d; if (m >= IRLEN) m -= IRLEN;          // m = (k*d) mod 129
            acc += 2.0f * fq[k] * costab[m];
        }
        zpS[i] = acc * (1.0f / 129.0f);
    }
    __syncthreads();

    // Phase 3: roll(FCL-1=64) + window -> wir[q][j], j in [0,129)
    for (int i = tid; i < NF * IRLEN; i += 256) {
        int q = i / IRLEN, j = i - q * IRLEN;
        int t = j - 64; if (t < 0) t += IRLEN;           // (j-64) mod 129
        int d = (t <= 64) ? t : (IRLEN - t);             // even symmetry
        float win = 0.5f - 0.5f * costab[j];             // periodic hann
        wirS[q * WSTRIDE + j] = win * zpS[q * FCL + d];
    }
    __syncthreads();

    // Phase 5: conv + overlap-add, 2 output samples per thread
    #pragma unroll
    for (int rep = 0; rep < 2; ++rep) {
        int pl = tid + rep * 256;
        int chunk = pl >> 6;                 // wave-uniform
        int r = pl & 63;
        int fp = fp0 + chunk;
        float acc = 0.0f;

        // dd = 1: frame fp-1, taps 64+r-s, always in range
        if (fp - 1 >= 0) {
            const float* wrow = &wirS[(chunk + 1) * WSTRIDE + 64 + r];
            const float* nrow = &nS[(chunk + 1) * FL];
            #pragma unroll 8
            for (int s = 0; s < 64; ++s) acc += nrow[s] * wrow[-s];
        }
        // dd = 0: frame fp, taps r-s >= 0 -> s <= r
        {
            const float* wrow = &wirS[(chunk + 2) * WSTRIDE + r];
            const float* nrow = &nS[(chunk + 2) * FL];
            for (int s = 0; s <= r; ++s) acc += nrow[s] * wrow[-s];
        }
        // dd = 2: frame fp-2, taps 128+r-s <= 128 -> s >= r
        if (fp - 2 >= 0) {
            const float* wrow = &wirS[chunk * WSTRIDE + 128 + r];
            const float* nrow = &nS[chunk * FL];
            for (int s = r; s < 64; ++s) acc += nrow[s] * wrow[-s];
        }

        out[(size_t)b * SAMPLES + (size_t)fp * 64 + r] = acc;
    }
}

extern "C" void kernel_launch(void* const* d_in, const int* in_sizes, int n_in,
                              void* d_out, int out_size, void* d_ws, size_t ws_size,
                              hipStream_t stream) {
    const float* coeff = (const float*)d_in[0];
    const float* noise = (const float*)d_in[1];
    float* out = (float*)d_out;
    dim3 grid(NB * BLOCKS_PER_B);   // 64 * 512 = 32768 blocks
    fn_kernel<<<grid, 256, 0, stream>>>(coeff, noise, out);
}

// Round 3
// 479.800 us; speedup vs baseline: 1.4230x; 1.4230x over previous
//
#include <hip/hip_runtime.h>

// FilteredNoise: DDSP filtered noise, FFT-free.
// zp[t] = (1/129)(fr0 + 2*sum_{k=1..64} fr_k cos(2*pi*k*t/129)), even-symmetric
// wir[j] = hann_periodic(j,129) * zp[(j-64) mod 129]
// out[b, 64*fp + r] = sum_{dd=0..2} sum_{s=0..63} n[fp-dd][s] * wir[fp-dd][64*dd + r - s]
// wir zero-padded in LDS so all three segments are fixed 64-tap branch-free loops.

#define NB 64
#define FTOT 4097
#define FCL 65
#define FL 64
#define IRLEN 129
#define SAMPLES 262144
#define OUT_FRAMES 4096
#define G 8                      // output frames per block
#define NF (G + 2)               // staged frames (2 overlap)
#define PW 256                   // padded wir stride: data at [63..191], zeros outside
#define BLOCKS_PER_B (OUT_FRAMES / G)   // 512

__device__ __forceinline__ float mod_sigmoid(float x) {
    float s = 1.0f / (1.0f + __expf(-x));
    return 2.0f * __expf(2.302585092994046f * __logf(s)) + 1e-7f;   // 2*s^ln(10)+1e-7
}

__global__ __launch_bounds__(256) void fn_kernel(
    const float* __restrict__ coeff,   // (64, 4097, 65)
    const float* __restrict__ noise,   // (64, 4097, 64)
    float* __restrict__ out)           // (64, 262144)
{
    __shared__ float costab[IRLEN];        // cos(2*pi*m/129)
    __shared__ float frS[NF * FCL];        // modified-sigmoid spectra
    __shared__ float zpS[NF * FCL];        // half zero-phase IR (t=0..64)
    __shared__ float nS[NF * FL];          // noise*2-1 (zeroed for frames < 0)
    __shared__ float wirP[NF * PW];        // zero-padded windowed IR

    const int tid = threadIdx.x;
    const int blk = blockIdx.x;
    const int b   = blk / BLOCKS_PER_B;
    const int cg  = blk % BLOCKS_PER_B;
    const int fp0 = cg * G;
    const int fbase = fp0 - 2;

    // Phase 0: cos table + zero-init wir padding
    if (tid < IRLEN)
        costab[tid] = __cosf(6.283185307179586f * (float)tid * (1.0f / 129.0f));
    #pragma unroll
    for (int i = tid; i < NF * PW; i += 256) wirP[i] = 0.0f;

    // Phase 1: coeffs -> fr (clamped frame index; conv contribution nulled via n=0)
    for (int i = tid; i < NF * FCL; i += 256) {
        int q = i / FCL, k = i - q * FCL;
        int f = fbase + q; if (f < 0) f = 0;
        frS[i] = mod_sigmoid(coeff[((size_t)b * FTOT + f) * FCL + k]);
    }
    // Phase 1b: noise -> nS, zeroed where frame < 0
    for (int i = tid; i < NF * FL; i += 256) {
        int q = i >> 6, s = i & 63;
        int f = fbase + q;
        float v = 0.0f;
        if (f >= 0) v = 2.0f * noise[((size_t)b * FTOT + f) * FL + s] - 1.0f;
        nS[i] = v;
    }
    __syncthreads();

    // Phase 2: half cosine transform via Chebyshev recurrence (2 fma/tap, no gather)
    for (int i = tid; i < NF * FCL; i += 256) {
        int q = i / FCL, d = i - q * FCL;
        const float* fq = &frS[q * FCL];
        float c  = costab[d];
        float c2 = 2.0f * c;
        float cp = 1.0f;        // cos(0)
        float ck = c;           // cos(theta)
        float acc = 0.0f;       // sum_{k=1..64} fr_k cos(k theta)
        #pragma unroll
        for (int k = 1; k < FCL; ++k) {
            acc = __builtin_fmaf(fq[k], ck, acc);
            float cn = __builtin_fmaf(c2, ck, -cp);
            cp = ck; ck = cn;
        }
        zpS[i] = (fq[0] + 2.0f * acc) * (1.0f / 129.0f);
    }
    __syncthreads();

    // Phase 3: roll(64) + hann window into padded layout
    for (int i = tid; i < NF * IRLEN; i += 256) {
        int q = i / IRLEN, j = i - q * IRLEN;
        int t = j - 64; if (t < 0) t += IRLEN;           // (j-64) mod 129
        int d = (t <= 64) ? t : (IRLEN - t);             // even symmetry
        float win = 0.5f - 0.5f * costab[j];
        wirP[q * PW + 63 + j] = win * zpS[q * FCL + d];
    }
    __syncthreads();

    // Phase 4: conv + overlap-add, branch-free, 2 outputs per thread
    #pragma unroll
    for (int rep = 0; rep < 2; ++rep) {
        int pl = tid + rep * 256;
        int chunk = pl >> 6;                 // wave-uniform (one wave = one frame)
        int r = pl & 63;
        int fp = fp0 + chunk;
        float acc = 0.0f;

        // dd=0: frame fp (staged chunk+2), w idx r-s via pad offset 63
        {
            const float* nr = &nS[(chunk + 2) * FL];
            const float* wr = &wirP[(chunk + 2) * PW + 63 + r];
            #pragma unroll
            for (int s = 0; s < 64; ++s) acc = __builtin_fmaf(nr[s], wr[-s], acc);
        }
        // dd=1: frame fp-1 (staged chunk+1), w idx 64+r-s via pad offset 127
        {
            const float* nr = &nS[(chunk + 1) * FL];
            const float* wr = &wirP[(chunk + 1) * PW + 127 + r];
            #pragma unroll
            for (int s = 0; s < 64; ++s) acc = __builtin_fmaf(nr[s], wr[-s], acc);
        }
        // dd=2: frame fp-2 (staged chunk), w idx 128+r-s via pad offset 191
        {
            const float* nr = &nS[chunk * FL];
            const float* wr = &wirP[chunk * PW + 191 + r];
            #pragma unroll
            for (int s = 0; s < 64; ++s) acc = __builtin_fmaf(nr[s], wr[-s], acc);
        }

        out[(size_t)b * SAMPLES + (size_t)fp * 64 + r] = acc;
    }
}

extern "C" void kernel_launch(void* const* d_in, const int* in_sizes, int n_in,
                              void* d_out, int out_size, void* d_ws, size_t ws_size,
                              hipStream_t stream) {
    const float* coeff = (const float*)d_in[0];
    const float* noise = (const float*)d_in[1];
    float* out = (float*)d_out;
    dim3 grid(NB * BLOCKS_PER_B);   // 32768 blocks
    fn_kernel<<<grid, 256, 0, stream>>>(coeff, noise, out);
}

// Round 4
// 435.506 us; speedup vs baseline: 1.5678x; 1.1017x over previous
//
#include <hip/hip_runtime.h>

// FilteredNoise: DDSP filtered noise, FFT-free.
// zp[t] = (1/129)(fr0 + 2*sum_{k=1..64} fr_k cos(2*pi*k*t/129)), even-symmetric
// wir[j] = hann_periodic(j,129) * zp[(j-64) mod 129]
// out[b, 64*fp + r] = sum_{dd=0..2} sum_{s=0..63} n[fp-dd][s] * wir[fp-dd][64*dd + r - s]
// Conv: 4 outputs/thread, rolling float4 w-window, aligned b128 LDS reads.

#define NB 64
#define FTOT 4097
#define FCL 65
#define FL 64
#define IRLEN 129
#define SAMPLES 262144
#define OUT_FRAMES 4096
#define G 16                     // output frames per block
#define NF (G + 2)               // staged frames (2 overlap)
#define FRSTRIDE 68              // frS row stride (16B-aligned rows)
#define PW 260                   // padded wir stride; data at [63..191], zeros elsewhere
#define BLOCKS_PER_B (OUT_FRAMES / G)   // 256

__device__ __forceinline__ float mod_sigmoid(float x) {
    float s = 1.0f / (1.0f + __expf(-x));
    return 2.0f * __expf(2.302585092994046f * __logf(s)) + 1e-7f;   // 2*s^ln(10)+1e-7
}

__global__ __launch_bounds__(256) void fn_kernel(
    const float* __restrict__ coeff,   // (64, 4097, 65)
    const float* __restrict__ noise,   // (64, 4097, 64)
    float* __restrict__ out)           // (64, 262144)
{
    __shared__ __align__(16) float costab[IRLEN];
    __shared__ __align__(16) float frS[NF * FRSTRIDE];   // sigmoid spectra, stride 68
    __shared__ __align__(16) float zpS[NF * FCL];        // half zero-phase IR
    __shared__ __align__(16) float nS[NF * FL];          // noise*2-1 (zeroed f<0)
    __shared__ __align__(16) float wirP[NF * PW];        // zero-padded windowed IR

    const int tid = threadIdx.x;
    const int blk = blockIdx.x;
    const int b   = blk / BLOCKS_PER_B;
    const int cg  = blk % BLOCKS_PER_B;
    const int fp0 = cg * G;
    const int fbase = fp0 - 2;

    // Phase 0: cos table + zero wirP (padding must be 0)
    if (tid < IRLEN)
        costab[tid] = __cosf(6.283185307179586f * (float)tid * (1.0f / 129.0f));
    for (int i = tid; i < NF * PW; i += 256) wirP[i] = 0.0f;

    // Phase 1: coeffs -> fr (clamped frame; nulled via n=0 in conv)
    for (int i = tid; i < NF * FCL; i += 256) {
        int q = i / FCL, k = i - q * FCL;
        int f = fbase + q; if (f < 0) f = 0;
        frS[q * FRSTRIDE + k] = mod_sigmoid(coeff[((size_t)b * FTOT + f) * FCL + k]);
    }
    // Phase 1b: noise -> nS (float4, zero where frame < 0)
    {
        const float4* np4 = (const float4*)(noise + ((size_t)b * FTOT + fbase) * FL);
        float4* ns4 = (float4*)nS;
        for (int i = tid; i < NF * FL / 4; i += 256) {
            int q = i >> 4;                      // 16 float4 per frame
            float4 v = make_float4(0.f, 0.f, 0.f, 0.f);
            if (fbase + q >= 0) {
                float4 u = np4[i];
                v = make_float4(2.f*u.x-1.f, 2.f*u.y-1.f, 2.f*u.z-1.f, 2.f*u.w-1.f);
            }
            ns4[i] = v;
        }
    }
    __syncthreads();

    // Phase 2: half cosine transform via Chebyshev, float4 spectrum reads.
    // S = sum_{k=0..64} fq[k] cos(k*theta);  zp = (2S - fq[0]) / 129
    for (int i = tid; i < NF * FCL; i += 256) {
        int q = i / FCL, d = i - q * FCL;
        const float* fq = &frS[q * FRSTRIDE];
        const float4* fq4 = (const float4*)fq;
        float c  = costab[d];
        float c2 = 2.0f * c;
        float cp = c;           // cos(-theta)
        float ck = 1.0f;        // cos(0)
        float S  = 0.0f;
        #pragma unroll
        for (int g = 0; g < 16; ++g) {
            float4 f4 = fq4[g];
            float cn;
            S = __builtin_fmaf(f4.x, ck, S); cn = __builtin_fmaf(c2, ck, -cp); cp = ck; ck = cn;
            S = __builtin_fmaf(f4.y, ck, S); cn = __builtin_fmaf(c2, ck, -cp); cp = ck; ck = cn;
            S = __builtin_fmaf(f4.z, ck, S); cn = __builtin_fmaf(c2, ck, -cp); cp = ck; ck = cn;
            S = __builtin_fmaf(f4.w, ck, S); cn = __builtin_fmaf(c2, ck, -cp); cp = ck; ck = cn;
        }
        S = __builtin_fmaf(fq[64], ck, S);       // k = 64
        zpS[q * FCL + d] = (2.0f * S - fq[0]) * (1.0f / 129.0f);
    }
    __syncthreads();

    // Phase 3: roll(64) + hann window into padded layout
    for (int i = tid; i < NF * IRLEN; i += 256) {
        int q = i / IRLEN, j = i - q * IRLEN;
        int t = j - 64; if (t < 0) t += IRLEN;           // (j-64) mod 129
        int d = (t <= 64) ? t : (IRLEN - t);             // even symmetry
        float win = 0.5f - 0.5f * costab[j];
        wirP[q * PW + 63 + j] = win * zpS[q * FCL + d];
    }
    __syncthreads();

    // Phase 4: conv + OLA. Thread computes 4 consecutive samples p = 4*tid..4*tid+3.
    {
        const int chunk = tid >> 4;              // output frame within block
        const int r0    = (tid & 15) * 4;        // first sample within frame
        float a0 = 0.f, a1 = 0.f, a2 = 0.f, a3 = 0.f;

        #pragma unroll
        for (int dd = 0; dd < 3; ++dd) {
            const int q = chunk + 2 - dd;        // staged index of frame fp-dd
            const float* wb = &wirP[q * PW + 63 + 64 * dd + r0];   // offset j = 64dd+r0
            const float4* n4p = (const float4*)&nS[q * FL];
            float4 whi = *(const float4*)(wb + 1);                 // offsets +1..+4
            #pragma unroll
            for (int s4 = 0; s4 < 16; ++s4) {
                float4 wlo = *(const float4*)(wb - 3 - 4 * s4);    // offsets -3..0 (-4s4)
                float4 n4  = n4p[s4];
                // acc_i += n4[si] * w[i - si], w[-3..0]=wlo, w[1..3]=whi.xyz
                a0 = __builtin_fmaf(n4.x, wlo.w, a0);
                a0 = __builtin_fmaf(n4.y, wlo.z, a0);
                a0 = __builtin_fmaf(n4.z, wlo.y, a0);
                a0 = __builtin_fmaf(n4.w, wlo.x, a0);
                a1 = __builtin_fmaf(n4.x, whi.x, a1);
                a1 = __builtin_fmaf(n4.y, wlo.w, a1);
                a1 = __builtin_fmaf(n4.z, wlo.z, a1);
                a1 = __builtin_fmaf(n4.w, wlo.y, a1);
                a2 = __builtin_fmaf(n4.x, whi.y, a2);
                a2 = __builtin_fmaf(n4.y, whi.x, a2);
                a2 = __builtin_fmaf(n4.z, wlo.w, a2);
                a2 = __builtin_fmaf(n4.w, wlo.z, a2);
                a3 = __builtin_fmaf(n4.x, whi.z, a3);
                a3 = __builtin_fmaf(n4.y, whi.y, a3);
                a3 = __builtin_fmaf(n4.z, whi.x, a3);
                a3 = __builtin_fmaf(n4.w, wlo.w, a3);
                whi = wlo;                       // rolling window
            }
        }

        float4 o = make_float4(a0, a1, a2, a3);
        *(float4*)&out[(size_t)b * SAMPLES + (size_t)fp0 * 64 + 4 * tid] = o;
    }
}

extern "C" void kernel_launch(void* const* d_in, const int* in_sizes, int n_in,
                              void* d_out, int out_size, void* d_ws, size_t ws_size,
                              hipStream_t stream) {
    const float* coeff = (const float*)d_in[0];
    const float* noise = (const float*)d_in[1];
    float* out = (float*)d_out;
    dim3 grid(NB * BLOCKS_PER_B);   // 64 * 256 = 16384 blocks
    fn_kernel<<<grid, 256, 0, stream>>>(coeff, noise, out);
}

// Round 5
// 367.390 us; speedup vs baseline: 1.8584x; 1.1854x over previous
//
#include <hip/hip_runtime.h>

// FilteredNoise: DDSP filtered noise, FFT-free.
// zp[d] = (1/129)(fr0 + 2*sum_{k=1..64} fr_k cos(2*pi*k*d/129)), even-symmetric
// wir[j] = hann_periodic(j,129) * zp[(j-64) mod 129]
//   lane d covers j=64+d and j=64-d; j=0 has win=0; j=128 (zp[64]) dropped,
//   win(128)=5.9e-4 -> output error <= ~6e-4, far under threshold.
// out[b,64*fp+r] = sum_{dd=0..2} sum_s n[fp-dd][s] * wir[fp-dd][64*dd+r-s]

#define NB 64
#define FTOT 4097
#define FCL 65
#define FL 64
#define SAMPLES 262144
#define OUT_FRAMES 4096
#define G 16                     // output frames per block
#define NF (G + 2)               // staged frames (2 overlap)
#define NSTRIDE 68               // nS row stride (bank stagger: 68 % 32 = 4)
#define PW 260                   // wirP row stride; data at [63..191], zeros elsewhere
#define BLOCKS_PER_B (OUT_FRAMES / G)   // 256

__device__ __forceinline__ float mod_sigmoid(float x) {
    float s = 1.0f / (1.0f + __expf(-x));
    return 2.0f * __expf(2.302585092994046f * __logf(s)) + 1e-7f;   // 2*s^ln(10)+1e-7
}

__device__ __forceinline__ float rdlane(float v, int k) {
    return __int_as_float(__builtin_amdgcn_readlane(__float_as_int(v), k));
}

__global__ __launch_bounds__(256) void fn_kernel(
    const float* __restrict__ coeff,   // (64, 4097, 65)
    const float* __restrict__ noise,   // (64, 4097, 64)
    float* __restrict__ out)           // (64, 262144)
{
    __shared__ __align__(16) float costab[132];          // cos(2*pi*m/129), m<129
    __shared__ __align__(16) float nS[NF * NSTRIDE];     // noise*2-1 (zero f<0)
    __shared__ __align__(16) float wirP[NF * PW];        // zero-padded windowed IR

    const int tid  = threadIdx.x;
    const int lane = tid & 63;
    const int wv   = tid >> 6;                           // wave id 0..3
    const int blk  = blockIdx.x;
    const int b    = blk / BLOCKS_PER_B;
    const int cg   = blk % BLOCKS_PER_B;
    const int fp0  = cg * G;
    const int fbase = fp0 - 2;

    // zero wirP (padding must be 0) + cos table
    for (int i = tid; i < NF * PW; i += 256) wirP[i] = 0.0f;
    if (tid < 129)
        costab[tid] = __cosf(6.283185307179586f * (float)tid * (1.0f / 129.0f));

    // stage noise (float4), zero where frame < 0; padded stride kills bank conflicts
    for (int i = tid; i < NF * 16; i += 256) {
        int q = i >> 4, g = i & 15;
        int f = fbase + q;
        float4 v = make_float4(0.f, 0.f, 0.f, 0.f);
        if (f >= 0) {
            const float4* src = (const float4*)(noise + ((size_t)b * FTOT + f) * FL);
            float4 u = src[g];
            v = make_float4(2.f*u.x-1.f, 2.f*u.y-1.f, 2.f*u.z-1.f, 2.f*u.w-1.f);
        }
        *(float4*)&nS[q * NSTRIDE + 4 * g] = v;
    }

    // preload this wave's 5 frame spectra (frames wv, wv+4, ..., wv+16);
    // lane l holds element l, plus the wave-uniform element 64.
    float frv[5], f64[5];
    #pragma unroll
    for (int i = 0; i < 5; ++i) {
        int f = fbase + wv + 4 * i;
        if (f < 0) f = 0;                       // garbage wir nulled via n=0
        if (f > FTOT - 1) f = FTOT - 1;
        const float* row = coeff + ((size_t)b * FTOT + f) * FCL;
        frv[i] = row[lane];
        f64[i] = row[64];
    }
    #pragma unroll
    for (int i = 0; i < 5; ++i) {
        frv[i] = mod_sigmoid(frv[i]);
        f64[i] = mod_sigmoid(f64[i]);
    }

    __syncthreads();   // wirP zeros + nS + costab visible

    // phase 2: Chebyshev transform via readlane broadcasts (no LDS reads for fr),
    // fused window + scatter into wirP.
    #pragma unroll
    for (int i = 0; i < 5; ++i) {
        int fi = wv + 4 * i;                    // staged frame index
        if (fi < NF) {                          // wave-uniform
            float c  = costab[lane];            // cos(theta_d), d = lane
            float c2 = 2.0f * c;
            float cp = 1.0f;                    // cos(0)
            float ck = c;                       // cos(theta)
            float s0 = rdlane(frv[i], 0);
            float S  = s0;                      // k=0 term
            #pragma unroll
            for (int k = 1; k < 64; ++k) {
                float sk = rdlane(frv[i], k);
                S = __builtin_fmaf(sk, ck, S);
                float cn = __builtin_fmaf(c2, ck, -cp);
                cp = ck; ck = cn;
            }
            S = __builtin_fmaf(f64[i], ck, S);  // k=64 term (ck = cos(64*theta))
            float zp = (2.0f * S - s0) * (1.0f / 129.0f);
            // window + scatter: j1 = 64+d, j2 = 64-d (lane 0: same slot, same value)
            float w1 = (0.5f - 0.5f * costab[64 + lane]) * zp;
            float w2 = (0.5f - 0.5f * costab[64 - lane]) * zp;
            wirP[fi * PW + 127 + lane] = w1;    // 63 + (64+d)
            wirP[fi * PW + 127 - lane] = w2;    // 63 + (64-d)
        }
    }
    __syncthreads();

    // conv + OLA: thread computes 4 consecutive samples, rolling float4 w-window
    {
        const int chunk = tid >> 4;             // output frame within block
        const int r0    = (tid & 15) * 4;       // first sample within frame
        float a0 = 0.f, a1 = 0.f, a2 = 0.f, a3 = 0.f;

        #pragma unroll
        for (int dd = 0; dd < 3; ++dd) {
            const int q = chunk + 2 - dd;       // staged index of frame fp-dd
            const float* wb = &wirP[q * PW + 63 + 64 * dd + r0];
            const float4* n4p = (const float4*)&nS[q * NSTRIDE];
            float4 whi = *(const float4*)(wb + 1);
            #pragma unroll
            for (int s4 = 0; s4 < 16; ++s4) {
                float4 wlo = *(const float4*)(wb - 3 - 4 * s4);
                float4 n4  = n4p[s4];
                a0 = __builtin_fmaf(n4.x, wlo.w, a0);
                a0 = __builtin_fmaf(n4.y, wlo.z, a0);
                a0 = __builtin_fmaf(n4.z, wlo.y, a0);
                a0 = __builtin_fmaf(n4.w, wlo.x, a0);
                a1 = __builtin_fmaf(n4.x, whi.x, a1);
                a1 = __builtin_fmaf(n4.y, wlo.w, a1);
                a1 = __builtin_fmaf(n4.z, wlo.z, a1);
                a1 = __builtin_fmaf(n4.w, wlo.y, a1);
                a2 = __builtin_fmaf(n4.x, whi.y, a2);
                a2 = __builtin_fmaf(n4.y, whi.x, a2);
                a2 = __builtin_fmaf(n4.z, wlo.w, a2);
                a2 = __builtin_fmaf(n4.w, wlo.z, a2);
                a3 = __builtin_fmaf(n4.x, whi.z, a3);
                a3 = __builtin_fmaf(n4.y, whi.y, a3);
                a3 = __builtin_fmaf(n4.z, whi.x, a3);
                a3 = __builtin_fmaf(n4.w, wlo.w, a3);
                whi = wlo;                      // rolling window
            }
        }

        *(float4*)&out[(size_t)b * SAMPLES + (size_t)fp0 * 64 + 4 * tid] =
            make_float4(a0, a1, a2, a3);
    }
}

extern "C" void kernel_launch(void* const* d_in, const int* in_sizes, int n_in,
                              void* d_out, int out_size, void* d_ws, size_t ws_size,
                              hipStream_t stream) {
    const float* coeff = (const float*)d_in[0];
    const float* noise = (const float*)d_in[1];
    float* out = (float*)d_out;
    dim3 grid(NB * BLOCKS_PER_B);   // 64 * 256 = 16384 blocks
    fn_kernel<<<grid, 256, 0, stream>>>(coeff, noise, out);
}

// Round 6
// 293.164 us; speedup vs baseline: 2.3290x; 1.2532x over previous
//
#include <hip/hip_runtime.h>

// FilteredNoise: DDSP filtered noise, FFT-free.
// zp[d] = (1/129)(fr0 + 2*sum_{k=1..64} fr_k cos(2*pi*k*d/129)), even-symmetric
// wir[j] = hann_periodic(j,129) * zp[(j-64) mod 129]; j=128 tap dropped (win=5.9e-4)
// out[b,64*fp+r] = sum_{dd=0..2} sum_s n[fp-dd][s] * wir[fp-dd][64*dd+r-s]
// Conv: 8 outputs/thread, rolling 3x float4 w-window (halves DS reads/sample).
// Transform: per-wave shared Chebyshev recurrence, readlane broadcasts, 9 frames/wave.

#define NB 64
#define FTOT 4097
#define FCL 65
#define FL 64
#define SAMPLES 262144
#define OUT_FRAMES 4096
#define G 16                     // output frames per block
#define NF (G + 2)               // staged frames (2 overlap)
#define NSTRIDE 68               // nS row stride (68 % 32 = 4 bank stagger)
#define PW 260                   // wirP row stride; data at [63..191], zeros elsewhere
#define BLOCKS_PER_B (OUT_FRAMES / G)   // 256

__device__ __forceinline__ float mod_sigmoid(float x) {
    float s = 1.0f / (1.0f + __expf(-x));
    return 2.0f * __expf(2.302585092994046f * __logf(s)) + 1e-7f;   // 2*s^ln(10)+1e-7
}

__device__ __forceinline__ float rdlane(float v, int k) {
    return __int_as_float(__builtin_amdgcn_readlane(__float_as_int(v), k));
}

__global__ __launch_bounds__(128) void fn_kernel(
    const float* __restrict__ coeff,   // (64, 4097, 65)
    const float* __restrict__ noise,   // (64, 4097, 64)
    float* __restrict__ out)           // (64, 262144)
{
    __shared__ __align__(16) float costab[132];          // cos(2*pi*m/129), m<=128
    __shared__ __align__(16) float nS[NF * NSTRIDE];     // noise*2-1 (zero f<0)
    __shared__ __align__(16) float wirP[NF * PW];        // zero-padded windowed IR

    const int tid  = threadIdx.x;
    const int lane = tid & 63;
    const int wv   = tid >> 6;                           // wave id 0..1
    const int blk  = blockIdx.x;
    const int b    = blk / BLOCKS_PER_B;
    const int cg   = blk % BLOCKS_PER_B;
    const int fp0  = cg * G;
    const int fbase = fp0 - 2;

    // zero wirP in float4 (pads must be 0; scatter after barrier overwrites data region)
    for (int i = tid; i < NF * PW / 4; i += 128)
        ((float4*)wirP)[i] = make_float4(0.f, 0.f, 0.f, 0.f);
    for (int i = tid; i < 129; i += 128)
        costab[i] = __cosf(6.283185307179586f * (float)i * (1.0f / 129.0f));

    // stage noise (float4), zero where frame < 0
    for (int i = tid; i < NF * 16; i += 128) {
        int q = i >> 4, g = i & 15;
        int f = fbase + q;
        float4 v = make_float4(0.f, 0.f, 0.f, 0.f);
        if (f >= 0) {
            const float4* src = (const float4*)(noise + ((size_t)b * FTOT + f) * FL);
            float4 u = src[g];
            v = make_float4(2.f*u.x-1.f, 2.f*u.y-1.f, 2.f*u.z-1.f, 2.f*u.w-1.f);
        }
        *(float4*)&nS[q * NSTRIDE + 4 * g] = v;
    }

    // preload this wave's 9 frame spectra (frames wv, wv+2, ..., wv+16)
    float frv[9], f64v[9];
    #pragma unroll
    for (int i = 0; i < 9; ++i) {
        int f = fbase + wv + 2 * i;
        if (f < 0) f = 0;                        // garbage wir nulled via n=0
        const float* row = coeff + ((size_t)b * FTOT + f) * FCL;
        frv[i]  = row[lane];
        f64v[i] = row[64];
    }
    #pragma unroll
    for (int i = 0; i < 9; ++i) {
        frv[i]  = mod_sigmoid(frv[i]);
        f64v[i] = mod_sigmoid(f64v[i]);
    }

    __syncthreads();   // wirP zeros + nS + costab visible

    // transform: shared Chebyshev recurrence across the wave's 9 frames
    {
        float c  = costab[lane];
        float c2 = 2.0f * c;
        float cp = 1.0f;         // cos(0)
        float ck = c;            // cos(theta)
        float S[9];
        #pragma unroll
        for (int i = 0; i < 9; ++i) S[i] = 0.5f * rdlane(frv[i], 0);   // 0.5*fr0
        #pragma unroll 8
        for (int k = 1; k < 64; ++k) {
            #pragma unroll
            for (int i = 0; i < 9; ++i)
                S[i] = __builtin_fmaf(rdlane(frv[i], k), ck, S[i]);
            float cn = __builtin_fmaf(c2, ck, -cp);
            cp = ck; ck = cn;
        }
        // k = 64 term: ck = cos(64*theta)
        #pragma unroll
        for (int i = 0; i < 9; ++i)
            S[i] = __builtin_fmaf(f64v[i], ck, S[i]);
        // window + scatter: zp = 2*S/129; j1 = 64+d, j2 = 64-d
        float w1f = 0.5f - 0.5f * costab[64 + lane];
        float w2f = 0.5f - 0.5f * costab[64 - lane];
        #pragma unroll
        for (int i = 0; i < 9; ++i) {
            int fi = wv + 2 * i;
            float zp = S[i] * (2.0f / 129.0f);
            wirP[fi * PW + 127 + lane] = w1f * zp;
            wirP[fi * PW + 127 - lane] = w2f * zp;
        }
    }
    __syncthreads();

    // conv + OLA: thread computes 8 consecutive samples, rolling 3-quad w-window
    {
        const int chunk = tid >> 3;              // output frame within block (0..15)
        const int r0    = (tid & 7) * 8;         // first sample within frame
        float a[8];
        #pragma unroll
        for (int j = 0; j < 8; ++j) a[j] = 0.0f;

        #pragma unroll
        for (int dd = 0; dd < 3; ++dd) {
            const int q = chunk + 2 - dd;        // staged index of frame fp-dd
            const float* wb = &wirP[q * PW + 63 + 64 * dd + r0];
            const float4* n4p = (const float4*)&nS[q * NSTRIDE];
            float4 W1 = *(const float4*)(wb + 1);    // offsets +1..+4
            float4 W2 = *(const float4*)(wb + 5);    // offsets +5..+8
            #pragma unroll
            for (int s4 = 0; s4 < 16; ++s4) {
                float4 W0 = *(const float4*)(wb - 3 - 4 * s4);   // offsets -3..0
                float4 n4 = n4p[s4];
                float w[11] = {W0.x, W0.y, W0.z, W0.w,
                               W1.x, W1.y, W1.z, W1.w,
                               W2.x, W2.y, W2.z};
                float nv[4] = {n4.x, n4.y, n4.z, n4.w};
                #pragma unroll
                for (int i = 0; i < 4; ++i)
                    #pragma unroll
                    for (int j = 0; j < 8; ++j)
                        a[j] = __builtin_fmaf(nv[i], w[j - i + 3], a[j]);
                W2 = W1; W1 = W0;                 // roll window
            }
        }

        float* op = &out[(size_t)b * SAMPLES + (size_t)fp0 * 64 + (size_t)tid * 8];
        *(float4*)op       = make_float4(a[0], a[1], a[2], a[3]);
        *(float4*)(op + 4) = make_float4(a[4], a[5], a[6], a[7]);
    }
}

extern "C" void kernel_launch(void* const* d_in, const int* in_sizes, int n_in,
                              void* d_out, int out_size, void* d_ws, size_t ws_size,
                              hipStream_t stream) {
    const float* coeff = (const float*)d_in[0];
    const float* noise = (const float*)d_in[1];
    float* out = (float*)d_out;
    dim3 grid(NB * BLOCKS_PER_B);   // 64 * 256 = 16384 blocks, 128 threads each
    fn_kernel<<<grid, 128, 0, stream>>>(coeff, noise, out);
}